// Round 13
// baseline (212.658 us; speedup 1.0000x reference)
//
#include <hip/hip_runtime.h>

typedef _Float16 f16;
typedef _Float16 h4 __attribute__((ext_vector_type(4)));
typedef _Float16 h8 __attribute__((ext_vector_type(8)));
typedef float f4 __attribute__((ext_vector_type(4)));

typedef const __attribute__((address_space(1))) char gchar;
typedef __attribute__((address_space(3))) char lchar;

#define B_ 4
#define S_ 2048
#define D_ 1024
#define H_ 1024

template <int N>
__device__ __forceinline__ void vmwait() {
  if constexpr (N == 0) asm volatile("s_waitcnt vmcnt(0)" ::: "memory");
  else if constexpr (N == 4) asm volatile("s_waitcnt vmcnt(4)" ::: "memory");
  else if constexpr (N == 6) asm volatile("s_waitcnt vmcnt(6)" ::: "memory");
}

// ---------------- cast x1,x2,x3,Wv f32->f16 : 16 elems/thread, exact grid (r10-verbatim) --------
__global__ __launch_bounds__(256) void cast_x(
    const float* __restrict__ x1, const float* __restrict__ x2, const float* __restrict__ x3,
    const float* __restrict__ wv,
    f16* __restrict__ o1, f16* __restrict__ o2, f16* __restrict__ o3, f16* __restrict__ ow) {
  const long g = blockIdx.x * 256L + threadIdx.x;
  const float* in;
  f16* out;
  long off;
  if (g < (3L << 19)) {
    const int w = (int)(g >> 19);
    off = (g & ((1L << 19) - 1)) * 16;
    in = w == 0 ? x1 : (w == 1 ? x2 : x3);
    out = w == 0 ? o1 : (w == 1 ? o2 : o3);
  } else {
    off = (g - (3L << 19)) * 16;
    in = wv;
    out = ow;
  }
  float4 a = *(const float4*)(in + off);
  float4 b = *(const float4*)(in + off + 4);
  float4 c = *(const float4*)(in + off + 8);
  float4 d = *(const float4*)(in + off + 12);
  h8 o0, o1v;
  o0[0] = (f16)a.x; o0[1] = (f16)a.y; o0[2] = (f16)a.z; o0[3] = (f16)a.w;
  o0[4] = (f16)b.x; o0[5] = (f16)b.y; o0[6] = (f16)b.z; o0[7] = (f16)b.w;
  o1v[0] = (f16)c.x; o1v[1] = (f16)c.y; o1v[2] = (f16)c.z; o1v[3] = (f16)c.w;
  o1v[4] = (f16)d.x; o1v[5] = (f16)d.y; o1v[6] = (f16)d.z; o1v[7] = (f16)d.w;
  *(h8*)(out + off) = o0;
  *(h8*)(out + off + 8) = o1v;
}

// ---------------- transpose-cast Wq, Wk (r10-verbatim) ----------------
__global__ __launch_bounds__(256) void wtrans(const float* __restrict__ wq,
                                              const float* __restrict__ wk,
                                              f16* __restrict__ oq, f16* __restrict__ ok) {
  __shared__ float t[32][33];
  const int bx = blockIdx.x;
  const float* in = (bx >> 10) ? wk : wq;
  f16* out = (bx >> 10) ? ok : oq;
  const int tile = bx & 1023;
  const int tr = tile >> 5, tc = tile & 31;
  const int tid = threadIdx.x;
  {
    const int r = tid >> 3, c4 = (tid & 7) * 4;
    float4 v = *(const float4*)(in + (long)(tr * 32 + r) * 1024 + tc * 32 + c4);
    t[r][c4] = v.x; t[r][c4 + 1] = v.y; t[r][c4 + 2] = v.z; t[r][c4 + 3] = v.w;
  }
  __syncthreads();
  {
    const int rr = tid >> 3, cc4 = (tid & 7) * 4;
    h4 o;
    o[0] = (f16)t[cc4][rr]; o[1] = (f16)t[cc4 + 1][rr];
    o[2] = (f16)t[cc4 + 2][rr]; o[3] = (f16)t[cc4 + 3][rr];
    *(h4*)(out + (long)(tc * 32 + rr) * 1024 + tr * 32 + cc4) = o;
  }
}

// ---------------- PROJ GEMM (r10-verbatim): C = A * B^T, 2-slot, syncthreads drain ----------
// OUT_MODE 1: f16 C[m*N+n] (+bz*sC)   OUT_MODE 2: f16 V^T per-batch
#define TILE 128
#define BK 32

template <int OUT_MODE>
__global__ __launch_bounds__(256) void gemm_abt(const f16* __restrict__ A,
                                                const f16* __restrict__ Bm,
                                                void* __restrict__ C,
                                                int M, int N, int K,
                                                long sA, long sB, long sC) {
  const int bz = blockIdx.z;
  A += (long)bz * sA;
  Bm += (long)bz * sB;

  __shared__ __align__(16) f16 lA[2][TILE * BK];
  __shared__ __align__(16) f16 lB[2][TILE * BK];

  const int tid = threadIdx.x;
  const int lane = tid & 63;
  const int w = tid >> 6;
  const int wr = w >> 1, wc = w & 1;
  const int m0 = blockIdx.x * TILE;
  const int n0 = blockIdx.y * TILE;

  const int lr = lane >> 2;
  const int lc = (lane & 3) * 8;
  const f16* Abase = A + (long)(m0 + lr) * K + lc;
  const f16* Bbase = Bm + (long)(n0 + lr) * K + lc;

  const int fr = lane & 15;
  const int kg = (lane >> 4) * 8;

  f4 acc[4][4] = {};

  auto STAGE = [&](int buf, int k0) {
#pragma unroll
    for (int c = 0; c < 2; ++c) {
      const int br = w * 32 + c * 16;
      __builtin_amdgcn_global_load_lds(
          (gchar*)(Abase + (long)br * K + k0),
          (lchar*)&lA[buf][br * BK], 16, 0, 0);
      __builtin_amdgcn_global_load_lds(
          (gchar*)(Bbase + (long)br * K + k0),
          (lchar*)&lB[buf][br * BK], 16, 0, 0);
    }
  };

  STAGE(0, 0);
  __syncthreads();

  int cur = 0;
  for (int k0 = 0; k0 < K; k0 += BK) {
    if (k0 + BK < K) STAGE(cur ^ 1, k0 + BK);

    h8 af[4], bf[4];
#pragma unroll
    for (int i = 0; i < 4; ++i) {
      af[i] = *(const h8*)&lA[cur][(wr * 64 + i * 16 + fr) * BK + kg];
      bf[i] = *(const h8*)&lB[cur][(wc * 64 + i * 16 + fr) * BK + kg];
    }
#pragma unroll
    for (int mi = 0; mi < 4; ++mi)
#pragma unroll
      for (int ni = 0; ni < 4; ++ni)
        acc[mi][ni] = __builtin_amdgcn_mfma_f32_16x16x32_f16(af[mi], bf[ni], acc[mi][ni], 0, 0, 0);

    __syncthreads();
    cur ^= 1;
  }

  const int fq = (lane >> 4) * 4;
#pragma unroll
  for (int mi = 0; mi < 4; ++mi) {
#pragma unroll
    for (int ni = 0; ni < 4; ++ni) {
#pragma unroll
      for (int i = 0; i < 4; ++i) {
        const int row = m0 + wr * 64 + mi * 16 + fq + i;
        const int col = n0 + wc * 64 + ni * 16 + fr;
        const float val = acc[mi][ni][i];
        if constexpr (OUT_MODE == 1) {
          f16* Cp = (f16*)C + (long)bz * sC;
          Cp[(long)row * N + col] = (f16)val;
        } else {
          f16* Cp = (f16*)C;
          const int b = row >> 11, sr = row & 2047;
          Cp[((long)b * N + col) * 2048 + sr] = (f16)val;
        }
      }
    }
  }
}

// ---------- WIDE Big-K GEMM: 128x256 tile, BK=32, 3-ring, counted vmcnt(6), T2 swizzle ----------
// 4 waves as 2x2; per-wave C = 64x128 (4x8 frags) -> 32 MFMA per K-step per wave.
// Slot = A 128x32 + B 256x32 = 24 KiB; 3 slots = 72 KiB -> 2 blocks/CU max.
// MODE 0: f32 C[m*N+n] (+bz*sC).  MODE 4: f16 C[m*N+n] (+bz*sC).
template <int MODE>
__global__ __launch_bounds__(256, 2) void gemm128w(const f16* __restrict__ A,
                                                   const f16* __restrict__ Bm,
                                                   void* __restrict__ C,
                                                   int N, int K,
                                                   long sA, long sB, long sC,
                                                   int gx, int gy) {
  __shared__ __align__(16) f16 smem[3 * 12288];  // 72 KiB

  const int cpx = gridDim.x >> 3;
  const int wgid = (blockIdx.x & 7) * cpx + (blockIdx.x >> 3);
  const int by = wgid % gy;
  const int bx = (wgid / gy) % gx;
  const int bz = wgid / (gy * gx);
  A += (long)bz * sA;
  Bm += (long)bz * sB;
  const int m0 = bx * 128, n0 = by * 256;

  const int tid = threadIdx.x;
  const int lane = tid & 63;
  const int w = tid >> 6;
  const int wm = w >> 1, wn = w & 1;   // 2x2 waves; per-wave 64 rows x 128 cols
  const int fr = lane & 15;
  const int g = lane >> 4;

  const int r0 = tid >> 2;
  const int s = tid & 3;

  auto STAGE = [&](int sl, int t) {
    const long k0 = (long)t * 32;
#pragma unroll
    for (int c = 0; c < 2; ++c) {
      const int row = c * 64 + r0;
      const int scol = (s ^ ((row >> 1) & 3)) * 8;
      __builtin_amdgcn_global_load_lds(
          (gchar*)(A + (long)(m0 + row) * K + k0 + scol),
          (lchar*)(smem + sl * 12288 + c * 2048 + tid * 8), 16, 0, 0);
    }
#pragma unroll
    for (int c = 0; c < 4; ++c) {
      const int row = c * 64 + r0;
      const int scol = (s ^ ((row >> 1) & 3)) * 8;
      __builtin_amdgcn_global_load_lds(
          (gchar*)(Bm + (long)(n0 + row) * K + k0 + scol),
          (lchar*)(smem + sl * 12288 + 4096 + c * 2048 + tid * 8), 16, 0, 0);
    }
  };

  auto RDA = [&](int sl, int r) -> h8 {
    return *(const h8*)(smem + sl * 12288 + (r * 4 + (g ^ ((r >> 1) & 3))) * 8);
  };
  auto RDB = [&](int sl, int r) -> h8 {
    return *(const h8*)(smem + sl * 12288 + 4096 + (r * 4 + (g ^ ((r >> 1) & 3))) * 8);
  };

  f4 acc[4][8] = {};
  const int NT = K >> 5;

  STAGE(0, 0);
  STAGE(1, 1);
  vmwait<6>();
  __builtin_amdgcn_s_barrier();

  int sl = 0;
  for (int t = 0; t < NT; ++t) {
    h8 af[4], bf[8];
#pragma unroll
    for (int i = 0; i < 4; ++i) af[i] = RDA(sl, wm * 64 + i * 16 + fr);
#pragma unroll
    for (int j = 0; j < 8; ++j) bf[j] = RDB(sl, wn * 128 + j * 16 + fr);
    const int ts = (t + 2 < NT) ? t + 2 : NT - 1;
    int ss = sl + 2; if (ss >= 3) ss -= 3;
    STAGE(ss, ts);
    vmwait<6>();                   // tile t+1's 6 loads retired; t+2's in flight
    asm volatile("s_waitcnt lgkmcnt(0)" ::: "memory");
    __builtin_amdgcn_sched_barrier(0);
    __builtin_amdgcn_s_setprio(1);
#pragma unroll
    for (int mi = 0; mi < 4; ++mi)
#pragma unroll
      for (int ni = 0; ni < 8; ++ni)
        acc[mi][ni] = __builtin_amdgcn_mfma_f32_16x16x32_f16(af[mi], bf[ni], acc[mi][ni], 0, 0, 0);
    __builtin_amdgcn_s_setprio(0);
    __builtin_amdgcn_s_barrier();
    sl = (sl + 1 == 3) ? 0 : sl + 1;
  }
  vmwait<0>();

  const int fq = g * 4;
#pragma unroll
  for (int mi = 0; mi < 4; ++mi) {
#pragma unroll
    for (int ni = 0; ni < 8; ++ni) {
#pragma unroll
      for (int i = 0; i < 4; ++i) {
        const int row = m0 + wm * 64 + mi * 16 + fq + i;
        const int col = n0 + wn * 128 + ni * 16 + fr;
        const float val = acc[mi][ni][i];
        if constexpr (MODE == 0) {
          float* Cp = (float*)C + (long)bz * sC;
          Cp[(long)row * N + col] = val;
        } else {
          f16* Cp = (f16*)C + (long)bz * sC;
          Cp[(long)row * N + col] = (f16)val;
        }
      }
    }
  }
}

// ---------------- fused scale + mask + softmax, scores f16 -> P f16 (r10-verbatim) -------------
__global__ __launch_bounds__(256) void softmax_rows(const f16* __restrict__ Sc,
                                                    const float* __restrict__ mask,
                                                    f16* __restrict__ P, float scale) {
  const long row = blockIdx.x;
  const f16* s = Sc + row * (long)S_;
  const float* mk = mask + row * (long)S_;
  const int t = threadIdx.x;

  h8 sv = *(const h8*)(s + t * 8);
  float4 b0 = *(const float4*)(mk + t * 8);
  float4 b1 = *(const float4*)(mk + t * 8 + 4);
  float v[8] = {(float)sv[0] * scale + b0.x, (float)sv[1] * scale + b0.y,
                (float)sv[2] * scale + b0.z, (float)sv[3] * scale + b0.w,
                (float)sv[4] * scale + b1.x, (float)sv[5] * scale + b1.y,
                (float)sv[6] * scale + b1.z, (float)sv[7] * scale + b1.w};

  float mx = v[0];
#pragma unroll
  for (int j = 1; j < 8; ++j) mx = fmaxf(mx, v[j]);
  for (int o = 32; o > 0; o >>= 1) mx = fmaxf(mx, __shfl_xor(mx, o));

  __shared__ float redm[4];
  __shared__ float reds[4];
  const int w = t >> 6;
  if ((t & 63) == 0) redm[w] = mx;
  __syncthreads();
  mx = fmaxf(fmaxf(redm[0], redm[1]), fmaxf(redm[2], redm[3]));

  float e[8];
  float sum = 0.f;
#pragma unroll
  for (int j = 0; j < 8; ++j) { e[j] = __expf(v[j] - mx); sum += e[j]; }
  for (int o = 32; o > 0; o >>= 1) sum += __shfl_xor(sum, o);
  if ((t & 63) == 0) reds[w] = sum;
  __syncthreads();
  sum = reds[0] + reds[1] + reds[2] + reds[3];
  const float inv = 1.0f / sum;

  h8 o;
#pragma unroll
  for (int j = 0; j < 8; ++j) o[j] = (f16)(e[j] * inv);
  *(h8*)(P + row * (long)S_ + t * 8) = o;
}

extern "C" void kernel_launch(void* const* d_in, const int* in_sizes, int n_in,
                              void* d_out, int out_size, void* d_ws, size_t ws_size,
                              hipStream_t stream) {
  const float* x1 = (const float*)d_in[0];
  const float* x2 = (const float*)d_in[1];
  const float* x3 = (const float*)d_in[2];
  const float* mask = (const float*)d_in[3];
  const float* Wq = (const float*)d_in[4];
  const float* Wk = (const float*)d_in[5];
  const float* Wv = (const float*)d_in[6];

  const long nx = (long)B_ * S_ * D_;
  const long nw = (long)H_ * D_;
  const long nqkv = (long)B_ * S_ * H_;
  const long nsc = (long)B_ * S_ * S_;

  char* ws = (char*)d_ws;
  f16* x1h = (f16*)ws; ws += nx * 2;
  f16* x2h = (f16*)ws; ws += nx * 2;     // scores B-operand
  f16* x3h = (f16*)ws; ws += nx * 2;
  f16* wvh = (f16*)ws; ws += nw * 2;
  f16* wqT = (f16*)ws; ws += nw * 2;
  f16* wkT = (f16*)ws; ws += nw * 2;
  f16* mt  = (f16*)ws; ws += nw * 2;     // Mt[e][d] = sum_h Wk[h][e] Wq[h][d]
  f16* qh  = (f16*)ws; ws += nqkv * 2;   // Qeff = x1 * Mt^T
  f16* vth = (f16*)ws; ws += nqkv * 2;   // V^T [b][h][s]
  f16* sc  = (f16*)ws; ws += nsc * 2;
  f16* ph  = (f16*)ws; ws += nsc * 2;

  cast_x<<<dim3(6400), 256, 0, stream>>>(x1, x2, x3, Wv, x1h, x2h, x3h, wvh);
  wtrans<<<dim3(2048), 256, 0, stream>>>(Wq, Wk, wqT, wkT);

  const dim3 blk(256);
  // Mt = WkT * WqT^T : 64 blocks
  gemm_abt<1><<<dim3(8, 8, 1), blk, 0, stream>>>(wkT, wqT, mt, 1024, 1024, 1024, 0, 0, 0);
  // Qeff = x1h * Mt^T
  gemm_abt<1><<<dim3(64, 8, 1), blk, 0, stream>>>(x1h, mt, qh, 8192, 1024, 1024, 0, 0, 0);
  // V^T projection
  gemm_abt<2><<<dim3(64, 8, 1), blk, 0, stream>>>(x3h, wvh, vth, 8192, 1024, 1024, 0, 0, 0);
  // scores[b] = Qeff[b] x2[b]^T -> f16 : WIDE tile, 16 x 8 x 4 = 512 blocks
  gemm128w<4><<<dim3(512), blk, 0, stream>>>(qh, x2h, sc, 2048, 1024,
                                             (long)S_ * H_, (long)S_ * D_, (long)S_ * S_, 16, 8);
  // P = softmax(scores * 1/sqrt(H) + mask)
  softmax_rows<<<B_ * S_, 256, 0, stream>>>(sc, mask, ph, 0.03125f);
  // out[b] = P[b] (V^T[b])^T : WIDE tile, 16 x 4 x 4 = 256 blocks
  gemm128w<0><<<dim3(256), blk, 0, stream>>>(ph, vth, d_out, 1024, 2048,
                                             (long)S_ * S_, (long)S_ * H_, (long)S_ * H_, 16, 4);
}

// Round 14
// 211.516 us; speedup vs baseline: 1.0054x; 1.0054x over previous
//
#include <hip/hip_runtime.h>

typedef _Float16 f16;
typedef _Float16 h4 __attribute__((ext_vector_type(4)));
typedef _Float16 h8 __attribute__((ext_vector_type(8)));
typedef float f4 __attribute__((ext_vector_type(4)));

typedef const __attribute__((address_space(1))) char gchar;
typedef __attribute__((address_space(3))) char lchar;

#define B_ 4
#define S_ 2048
#define D_ 1024
#define H_ 1024

template <int N>
__device__ __forceinline__ void vmwait() {
  if constexpr (N == 0) asm volatile("s_waitcnt vmcnt(0)" ::: "memory");
  else if constexpr (N == 4) asm volatile("s_waitcnt vmcnt(4)" ::: "memory");
  else if constexpr (N == 6) asm volatile("s_waitcnt vmcnt(6)" ::: "memory");
}

// ---------------- cast x1,x2,x3,Wv f32->f16 : 16 elems/thread, exact grid ----------------
__global__ __launch_bounds__(256) void cast_x(
    const float* __restrict__ x1, const float* __restrict__ x2, const float* __restrict__ x3,
    const float* __restrict__ wv,
    f16* __restrict__ o1, f16* __restrict__ o2, f16* __restrict__ o3, f16* __restrict__ ow) {
  const long g = blockIdx.x * 256L + threadIdx.x;
  const float* in;
  f16* out;
  long off;
  if (g < (3L << 19)) {
    const int w = (int)(g >> 19);
    off = (g & ((1L << 19) - 1)) * 16;
    in = w == 0 ? x1 : (w == 1 ? x2 : x3);
    out = w == 0 ? o1 : (w == 1 ? o2 : o3);
  } else {
    off = (g - (3L << 19)) * 16;
    in = wv;
    out = ow;
  }
  float4 a = *(const float4*)(in + off);
  float4 b = *(const float4*)(in + off + 4);
  float4 c = *(const float4*)(in + off + 8);
  float4 d = *(const float4*)(in + off + 12);
  h8 o0, o1v;
  o0[0] = (f16)a.x; o0[1] = (f16)a.y; o0[2] = (f16)a.z; o0[3] = (f16)a.w;
  o0[4] = (f16)b.x; o0[5] = (f16)b.y; o0[6] = (f16)b.z; o0[7] = (f16)b.w;
  o1v[0] = (f16)c.x; o1v[1] = (f16)c.y; o1v[2] = (f16)c.z; o1v[3] = (f16)c.w;
  o1v[4] = (f16)d.x; o1v[5] = (f16)d.y; o1v[6] = (f16)d.z; o1v[7] = (f16)d.w;
  *(h8*)(out + off) = o0;
  *(h8*)(out + off + 8) = o1v;
}

// ---------------- transpose-cast Wq, Wk ----------------
__global__ __launch_bounds__(256) void wtrans(const float* __restrict__ wq,
                                              const float* __restrict__ wk,
                                              f16* __restrict__ oq, f16* __restrict__ ok) {
  __shared__ float t[32][33];
  const int bx = blockIdx.x;
  const float* in = (bx >> 10) ? wk : wq;
  f16* out = (bx >> 10) ? ok : oq;
  const int tile = bx & 1023;
  const int tr = tile >> 5, tc = tile & 31;
  const int tid = threadIdx.x;
  {
    const int r = tid >> 3, c4 = (tid & 7) * 4;
    float4 v = *(const float4*)(in + (long)(tr * 32 + r) * 1024 + tc * 32 + c4);
    t[r][c4] = v.x; t[r][c4 + 1] = v.y; t[r][c4 + 2] = v.z; t[r][c4 + 3] = v.w;
  }
  __syncthreads();
  {
    const int rr = tid >> 3, cc4 = (tid & 7) * 4;
    h4 o;
    o[0] = (f16)t[cc4][rr]; o[1] = (f16)t[cc4 + 1][rr];
    o[2] = (f16)t[cc4 + 2][rr]; o[3] = (f16)t[cc4 + 3][rr];
    *(h4*)(out + (long)(tc * 32 + rr) * 1024 + tr * 32 + cc4) = o;
  }
}

// ---------------- PROJ GEMM: C = A * B^T, 2-slot, syncthreads drain ----------
// OUT_MODE 1: f16 C[m*N+n] (+bz*sC)   OUT_MODE 2: f16 V^T per-batch
#define TILE 128
#define BK 32

template <int OUT_MODE>
__global__ __launch_bounds__(256) void gemm_abt(const f16* __restrict__ A,
                                                const f16* __restrict__ Bm,
                                                void* __restrict__ C,
                                                int M, int N, int K,
                                                long sA, long sB, long sC) {
  const int bz = blockIdx.z;
  A += (long)bz * sA;
  Bm += (long)bz * sB;

  __shared__ __align__(16) f16 lA[2][TILE * BK];
  __shared__ __align__(16) f16 lB[2][TILE * BK];

  const int tid = threadIdx.x;
  const int lane = tid & 63;
  const int w = tid >> 6;
  const int wr = w >> 1, wc = w & 1;
  const int m0 = blockIdx.x * TILE;
  const int n0 = blockIdx.y * TILE;

  const int lr = lane >> 2;
  const int lc = (lane & 3) * 8;
  const f16* Abase = A + (long)(m0 + lr) * K + lc;
  const f16* Bbase = Bm + (long)(n0 + lr) * K + lc;

  const int fr = lane & 15;
  const int kg = (lane >> 4) * 8;

  f4 acc[4][4] = {};

  auto STAGE = [&](int buf, int k0) {
#pragma unroll
    for (int c = 0; c < 2; ++c) {
      const int br = w * 32 + c * 16;
      __builtin_amdgcn_global_load_lds(
          (gchar*)(Abase + (long)br * K + k0),
          (lchar*)&lA[buf][br * BK], 16, 0, 0);
      __builtin_amdgcn_global_load_lds(
          (gchar*)(Bbase + (long)br * K + k0),
          (lchar*)&lB[buf][br * BK], 16, 0, 0);
    }
  };

  STAGE(0, 0);
  __syncthreads();

  int cur = 0;
  for (int k0 = 0; k0 < K; k0 += BK) {
    if (k0 + BK < K) STAGE(cur ^ 1, k0 + BK);

    h8 af[4], bf[4];
#pragma unroll
    for (int i = 0; i < 4; ++i) {
      af[i] = *(const h8*)&lA[cur][(wr * 64 + i * 16 + fr) * BK + kg];
      bf[i] = *(const h8*)&lB[cur][(wc * 64 + i * 16 + fr) * BK + kg];
    }
#pragma unroll
    for (int mi = 0; mi < 4; ++mi)
#pragma unroll
      for (int ni = 0; ni < 4; ++ni)
        acc[mi][ni] = __builtin_amdgcn_mfma_f32_16x16x32_f16(af[mi], bf[ni], acc[mi][ni], 0, 0, 0);

    __syncthreads();
    cur ^= 1;
  }

  const int fq = (lane >> 4) * 4;
#pragma unroll
  for (int mi = 0; mi < 4; ++mi) {
#pragma unroll
    for (int ni = 0; ni < 4; ++ni) {
#pragma unroll
      for (int i = 0; i < 4; ++i) {
        const int row = m0 + wr * 64 + mi * 16 + fq + i;
        const int col = n0 + wc * 64 + ni * 16 + fr;
        const float val = acc[mi][ni][i];
        if constexpr (OUT_MODE == 1) {
          f16* Cp = (f16*)C + (long)bz * sC;
          Cp[(long)row * N + col] = (f16)val;
        } else {
          f16* Cp = (f16*)C;
          const int b = row >> 11, sr = row & 2047;
          Cp[((long)b * N + col) * 2048 + sr] = (f16)val;
        }
      }
    }
  }
}

// ---------- WIDE Big-K GEMM: 128x256 tile, BK=32, 3-ring, counted vmcnt(6), T2 swizzle ----------
// 4 waves as 2x2; per-wave C = 64x128 (4x8 frags) -> 32 MFMA per K-step per wave.
// MODE 5: U = exp(val*scale + mask) -> f16  (scores; xtra = mask f32, stride sC per batch)
// MODE 6: f32 C = val * invr[bz*2048+row]   (PV; xtra = invr)
template <int MODE>
__global__ __launch_bounds__(256, 2) void gemm128w(const f16* __restrict__ A,
                                                   const f16* __restrict__ Bm,
                                                   void* __restrict__ C,
                                                   const float* __restrict__ xtra,
                                                   int N, int K,
                                                   long sA, long sB, long sC,
                                                   int gx, int gy) {
  __shared__ __align__(16) f16 smem[3 * 12288];  // 72 KiB

  const int cpx = gridDim.x >> 3;
  const int wgid = (blockIdx.x & 7) * cpx + (blockIdx.x >> 3);
  const int by = wgid % gy;
  const int bx = (wgid / gy) % gx;
  const int bz = wgid / (gy * gx);
  A += (long)bz * sA;
  Bm += (long)bz * sB;
  const int m0 = bx * 128, n0 = by * 256;

  const int tid = threadIdx.x;
  const int lane = tid & 63;
  const int w = tid >> 6;
  const int wm = w >> 1, wn = w & 1;   // 2x2 waves; per-wave 64 rows x 128 cols
  const int fr = lane & 15;
  const int g = lane >> 4;

  const int r0 = tid >> 2;
  const int s = tid & 3;

  auto STAGE = [&](int sl, int t) {
    const long k0 = (long)t * 32;
#pragma unroll
    for (int c = 0; c < 2; ++c) {
      const int row = c * 64 + r0;
      const int scol = (s ^ ((row >> 1) & 3)) * 8;
      __builtin_amdgcn_global_load_lds(
          (gchar*)(A + (long)(m0 + row) * K + k0 + scol),
          (lchar*)(smem + sl * 12288 + c * 2048 + tid * 8), 16, 0, 0);
    }
#pragma unroll
    for (int c = 0; c < 4; ++c) {
      const int row = c * 64 + r0;
      const int scol = (s ^ ((row >> 1) & 3)) * 8;
      __builtin_amdgcn_global_load_lds(
          (gchar*)(Bm + (long)(n0 + row) * K + k0 + scol),
          (lchar*)(smem + sl * 12288 + 4096 + c * 2048 + tid * 8), 16, 0, 0);
    }
  };

  auto RDA = [&](int sl, int r) -> h8 {
    return *(const h8*)(smem + sl * 12288 + (r * 4 + (g ^ ((r >> 1) & 3))) * 8);
  };
  auto RDB = [&](int sl, int r) -> h8 {
    return *(const h8*)(smem + sl * 12288 + 4096 + (r * 4 + (g ^ ((r >> 1) & 3))) * 8);
  };

  f4 acc[4][8] = {};
  const int NT = K >> 5;

  STAGE(0, 0);
  STAGE(1, 1);
  vmwait<6>();
  __builtin_amdgcn_s_barrier();

  int sl = 0;
  for (int t = 0; t < NT; ++t) {
    h8 af[4], bf[8];
#pragma unroll
    for (int i = 0; i < 4; ++i) af[i] = RDA(sl, wm * 64 + i * 16 + fr);
#pragma unroll
    for (int j = 0; j < 8; ++j) bf[j] = RDB(sl, wn * 128 + j * 16 + fr);
    const int ts = (t + 2 < NT) ? t + 2 : NT - 1;
    int ss = sl + 2; if (ss >= 3) ss -= 3;
    STAGE(ss, ts);
    vmwait<6>();                   // tile t+1's 6 loads retired; t+2's in flight
    asm volatile("s_waitcnt lgkmcnt(0)" ::: "memory");
    __builtin_amdgcn_sched_barrier(0);
    __builtin_amdgcn_s_setprio(1);
#pragma unroll
    for (int mi = 0; mi < 4; ++mi)
#pragma unroll
      for (int ni = 0; ni < 8; ++ni)
        acc[mi][ni] = __builtin_amdgcn_mfma_f32_16x16x32_f16(af[mi], bf[ni], acc[mi][ni], 0, 0, 0);
    __builtin_amdgcn_s_setprio(0);
    __builtin_amdgcn_s_barrier();
    sl = (sl + 1 == 3) ? 0 : sl + 1;
  }
  vmwait<0>();

  const int fq = g * 4;
#pragma unroll
  for (int mi = 0; mi < 4; ++mi) {
#pragma unroll
    for (int ni = 0; ni < 8; ++ni) {
#pragma unroll
      for (int i = 0; i < 4; ++i) {
        const int row = m0 + wm * 64 + mi * 16 + fq + i;
        const int col = n0 + wn * 128 + ni * 16 + fr;
        const float val = acc[mi][ni][i];
        if constexpr (MODE == 5) {
          // U = exp(score*scale + mask); shift-free softmax numerator (bounded by e^|max|)
          const float* mk = xtra + (long)bz * sC;
          f16* Cp = (f16*)C + (long)bz * sC;
          Cp[(long)row * N + col] =
              (f16)__expf(val * 0.03125f + mk[(long)row * N + col]);
        } else {
          float* Cp = (float*)C + (long)bz * sC;
          Cp[(long)row * N + col] = val * xtra[bz * 2048 + row];
        }
      }
    }
  }
}

// ---------------- rowsum of U -> invr = 1/sum (one block per row) ----------------
__global__ __launch_bounds__(256) void rowsum_inv(const f16* __restrict__ U,
                                                  float* __restrict__ invr) {
  const long row = blockIdx.x;
  const f16* u = U + row * (long)S_;
  const int t = threadIdx.x;
  h8 v = *(const h8*)(u + t * 8);
  float s = 0.f;
#pragma unroll
  for (int j = 0; j < 8; ++j) s += (float)v[j];
  for (int o = 32; o > 0; o >>= 1) s += __shfl_xor(s, o);
  __shared__ float red[4];
  if ((t & 63) == 0) red[t >> 6] = s;
  __syncthreads();
  if (t == 0) invr[row] = 1.0f / (red[0] + red[1] + red[2] + red[3]);
}

extern "C" void kernel_launch(void* const* d_in, const int* in_sizes, int n_in,
                              void* d_out, int out_size, void* d_ws, size_t ws_size,
                              hipStream_t stream) {
  const float* x1 = (const float*)d_in[0];
  const float* x2 = (const float*)d_in[1];
  const float* x3 = (const float*)d_in[2];
  const float* mask = (const float*)d_in[3];
  const float* Wq = (const float*)d_in[4];
  const float* Wk = (const float*)d_in[5];
  const float* Wv = (const float*)d_in[6];

  const long nx = (long)B_ * S_ * D_;
  const long nw = (long)H_ * D_;
  const long nqkv = (long)B_ * S_ * H_;
  const long nsc = (long)B_ * S_ * S_;

  char* ws = (char*)d_ws;
  f16* x1h = (f16*)ws; ws += nx * 2;
  f16* x2h = (f16*)ws; ws += nx * 2;     // scores B-operand
  f16* x3h = (f16*)ws; ws += nx * 2;
  f16* wvh = (f16*)ws; ws += nw * 2;
  f16* wqT = (f16*)ws; ws += nw * 2;
  f16* wkT = (f16*)ws; ws += nw * 2;
  f16* mt  = (f16*)ws; ws += nw * 2;     // Mt[e][d] = sum_h Wk[h][e] Wq[h][d]
  f16* qh  = (f16*)ws; ws += nqkv * 2;   // Qeff = x1 * Mt^T
  f16* vth = (f16*)ws; ws += nqkv * 2;   // V^T [b][h][s]
  f16* sc  = (f16*)ws; ws += nsc * 2;    // U = exp(scores*scale + mask), f16
  float* invr = (float*)ws; ws += (long)B_ * S_ * 4;

  cast_x<<<dim3(6400), 256, 0, stream>>>(x1, x2, x3, Wv, x1h, x2h, x3h, wvh);
  wtrans<<<dim3(2048), 256, 0, stream>>>(Wq, Wk, wqT, wkT);

  const dim3 blk(256);
  // Mt = WkT * WqT^T : 64 blocks
  gemm_abt<1><<<dim3(8, 8, 1), blk, 0, stream>>>(wkT, wqT, mt, 1024, 1024, 1024, 0, 0, 0);
  // Qeff = x1h * Mt^T
  gemm_abt<1><<<dim3(64, 8, 1), blk, 0, stream>>>(x1h, mt, qh, 8192, 1024, 1024, 0, 0, 0);
  // V^T projection
  gemm_abt<2><<<dim3(64, 8, 1), blk, 0, stream>>>(x3h, wvh, vth, 8192, 1024, 1024, 0, 0, 0);
  // U[b] = exp(Qeff[b] x2[b]^T * scale + mask[b]) -> f16 : 16 x 8 x 4 = 512 blocks
  gemm128w<5><<<dim3(512), blk, 0, stream>>>(qh, x2h, sc, mask, 2048, 1024,
                                             (long)S_ * H_, (long)S_ * D_, (long)S_ * S_, 16, 8);
  // invr[row] = 1 / rowsum(U)
  rowsum_inv<<<dim3(B_ * S_), blk, 0, stream>>>(sc, invr);
  // out[b] = (U[b] (V^T[b])^T) * invr : 16 x 4 x 4 = 256 blocks
  gemm128w<6><<<dim3(256), blk, 0, stream>>>(sc, vth, d_out, invr, 1024, 2048,
                                             (long)S_ * S_, (long)S_ * H_, (long)S_ * H_, 16, 4);
}